// Round 2
// baseline (967.848 us; speedup 1.0000x reference)
//
#include <hip/hip_runtime.h>
#include <hip/hip_bf16.h>

#define DIV_UP(a,b) (((a)+(b)-1)/(b))

// ---------------- preprocessing: degree, dinv, CSR-by-dst ----------------

__global__ __launch_bounds__(256) void k_count(const int* __restrict__ dst, int* __restrict__ counts, int E){
  int e = blockIdx.x*256 + threadIdx.x;
  if (e < E) atomicAdd(&counts[dst[e]], 1);
}

__global__ __launch_bounds__(256) void k_dinv(const int* __restrict__ counts, float* __restrict__ dinv, int N){
  int n = blockIdx.x*256 + threadIdx.x;
  if (n < N) dinv[n] = rsqrtf((float)(counts[n] + 1));  // +1 = self-loop
}

__global__ __launch_bounds__(1024) void k_scan1(const int* __restrict__ counts, int* __restrict__ rowptr,
                                                int* __restrict__ bsum, int N){
  __shared__ int s[1024];
  int t = threadIdx.x, g = blockIdx.x*1024 + t;
  int v = (g < N) ? counts[g] : 0;
  s[t] = v; __syncthreads();
  for (int off = 1; off < 1024; off <<= 1){
    int u = (t >= off) ? s[t-off] : 0; __syncthreads();
    s[t] += u; __syncthreads();
  }
  if (g < N) rowptr[g] = s[t] - v;           // block-local exclusive scan
  if (t == 1023) bsum[blockIdx.x] = s[1023];
}

__global__ __launch_bounds__(128) void k_scan2(const int* __restrict__ bsum, int* __restrict__ boff,
                                               int nb, int* __restrict__ rowptr, int N){
  __shared__ int s[128];
  int t = threadIdx.x;
  int v = (t < nb) ? bsum[t] : 0;
  s[t] = v; __syncthreads();
  for (int off = 1; off < 128; off <<= 1){
    int u = (t >= off) ? s[t-off] : 0; __syncthreads();
    s[t] += u; __syncthreads();
  }
  if (t < nb) boff[t] = s[t] - v;            // exclusive over block sums
  if (t == 127) rowptr[N] = s[127];          // total = E
}

__global__ __launch_bounds__(1024) void k_scan3(int* __restrict__ rowptr, const int* __restrict__ boff, int N){
  int g = blockIdx.x*1024 + threadIdx.x;
  if (g < N) rowptr[g] += boff[blockIdx.x];
}

__global__ __launch_bounds__(256) void k_fill(const int* __restrict__ src, const int* __restrict__ dst,
                                              const int* __restrict__ rowptr, int* __restrict__ fill,
                                              int* __restrict__ csr, int E){
  int e = blockIdx.x*256 + threadIdx.x;
  if (e < E){
    int d = dst[e];
    int pos = rowptr[d] + atomicAdd(&fill[d], 1);
    csr[pos] = src[e];
  }
}

// ---------------- fused 64-wide aggregation of raw x: out = dinv[n]*(sum dinv[s]x[s] + dinv[n]x[n]) ----------------
__global__ __launch_bounds__(256) void k_agg64x(const float* __restrict__ x, const int* __restrict__ rowptr,
                                                const int* __restrict__ csr, const float* __restrict__ dinv,
                                                float* __restrict__ out, int N){
  const int tid = threadIdx.x;
  const int node = blockIdx.x*16 + (tid >> 4);
  if (node >= N) return;
  const int c = (tid & 15) * 4;
  const float* xc = x + c;
  const float dn = dinv[node];
  float4 s = *(const float4*)(x + (size_t)node*64 + c);
  float ax = dn*s.x, ay = dn*s.y, az = dn*s.z, aw = dn*s.w;  // self term (dinv[n]*x[n])
  int e = rowptr[node], end = rowptr[node+1];
  for (; e + 4 <= end; e += 4){
    int s0 = csr[e], s1 = csr[e+1], s2 = csr[e+2], s3 = csr[e+3];
    float d0 = dinv[s0], d1 = dinv[s1], d2 = dinv[s2], d3 = dinv[s3];
    float4 v0 = *(const float4*)(xc + (size_t)s0*64);
    float4 v1 = *(const float4*)(xc + (size_t)s1*64);
    float4 v2 = *(const float4*)(xc + (size_t)s2*64);
    float4 v3 = *(const float4*)(xc + (size_t)s3*64);
    ax += d0*v0.x + d1*v1.x + d2*v2.x + d3*v3.x;
    ay += d0*v0.y + d1*v1.y + d2*v2.y + d3*v3.y;
    az += d0*v0.z + d1*v1.z + d2*v2.z + d3*v3.z;
    aw += d0*v0.w + d1*v1.w + d2*v2.w + d3*v3.w;
  }
  for (; e < end; ++e){
    int s0 = csr[e];
    float d0 = dinv[s0];
    float4 v = *(const float4*)(xc + (size_t)s0*64);
    ax += d0*v.x; ay += d0*v.y; az += d0*v.z; aw += d0*v.w;
  }
  float4 o = {dn*ax, dn*ay, dn*az, dn*aw};
  *(float4*)(out + (size_t)node*64 + c) = o;
}

// ---------------- GEMM: out[N,128] = H[N,FIN] @ W[FIN,128]; 128x128 tile, 8x8 micro-tile ----------------
template<int FIN>
__global__ __launch_bounds__(256) void k_gemm2(const float* __restrict__ H, const float* __restrict__ W,
                                               const float* __restrict__ bias, const float* __restrict__ dinv,
                                               float* __restrict__ out, int N, int relu){
  constexpr int KC = 32;
  __shared__ float At[KC][129];   // transposed A chunk: At[k][row], +1 pad
  __shared__ float Bs[KC][128];   // W chunk
  const int tid = threadIdx.x;
  const int tr = tid >> 4, tc = tid & 15;   // rows 8tr..8tr+7; cols {4tc..4tc+3, 64+4tc..64+4tc+3}
  const int row0 = blockIdx.x * 128;

  float acc[8][8];
  #pragma unroll
  for (int i = 0; i < 8; ++i)
    #pragma unroll
    for (int j = 0; j < 8; ++j) acc[i][j] = 0.f;

  for (int k0 = 0; k0 < FIN; k0 += KC){
    // stage A (coalesced read, transposed write; banks (4c+j+rr)%32 -> <=2-way, free)
    #pragma unroll
    for (int it = 0; it < 4; ++it){
      int idx = it*256 + tid;
      int rr = idx >> 3;           // 0..127
      int c4 = (idx & 7) * 4;      // 0..28
      int grow = row0 + rr; if (grow >= N) grow = N - 1;
      float4 v = *(const float4*)(H + (size_t)grow*FIN + k0 + c4);
      At[c4+0][rr] = v.x; At[c4+1][rr] = v.y; At[c4+2][rr] = v.z; At[c4+3][rr] = v.w;
    }
    // stage B
    #pragma unroll
    for (int it = 0; it < 4; ++it){
      int idx = it*1024 + tid*4;
      int kk = idx >> 7, cc = idx & 127;
      *(float4*)&Bs[kk][cc] = *(const float4*)(W + (size_t)(k0+kk)*128 + cc);
    }
    __syncthreads();
    #pragma unroll
    for (int kk = 0; kk < KC; ++kk){
      float4 a0 = *(const float4*)&At[kk][8*tr];
      float4 a1 = *(const float4*)&At[kk][8*tr + 4];
      float4 b0 = *(const float4*)&Bs[kk][4*tc];
      float4 b1 = *(const float4*)&Bs[kk][64 + 4*tc];
      float a[8] = {a0.x,a0.y,a0.z,a0.w,a1.x,a1.y,a1.z,a1.w};
      float b[8] = {b0.x,b0.y,b0.z,b0.w,b1.x,b1.y,b1.z,b1.w};
      #pragma unroll
      for (int i = 0; i < 8; ++i)
        #pragma unroll
        for (int j = 0; j < 8; ++j)
          acc[i][j] += a[i]*b[j];
    }
    __syncthreads();
  }

  float bl[8] = {0,0,0,0,0,0,0,0};
  if (bias){
    #pragma unroll
    for (int j = 0; j < 4; ++j){ bl[j] = bias[4*tc + j]; bl[4+j] = bias[64 + 4*tc + j]; }
  }
  #pragma unroll
  for (int i = 0; i < 8; ++i){
    int r = row0 + 8*tr + i;
    if (r < N){
      float sc = dinv ? dinv[r] : 1.f;
      float o[8];
      #pragma unroll
      for (int j = 0; j < 8; ++j){
        o[j] = acc[i][j]*sc + bl[j];
        if (relu) o[j] = fmaxf(o[j], 0.f);
      }
      float4 u0 = {o[0],o[1],o[2],o[3]}, u1 = {o[4],o[5],o[6],o[7]};
      *(float4*)(out + (size_t)r*128 + 4*tc)      = u0;
      *(float4*)(out + (size_t)r*128 + 64 + 4*tc) = u1;
    }
  }
}

// ---------------- 128-wide CSR aggregation: out[n] = relu(dinv[n]*(sum p[src] + p[n]) + bias) ----------------
__global__ __launch_bounds__(256) void k_agg128(const float* __restrict__ p, const int* __restrict__ rowptr,
                                                const int* __restrict__ csr, const float* __restrict__ dinv,
                                                const float* __restrict__ bias, float* __restrict__ out, int N){
  const int tid = threadIdx.x;
  const int node = blockIdx.x*16 + (tid >> 4);
  if (node >= N) return;
  const int c = (tid & 15) * 8;
  const float* pc = p + c;
  const float* ps = p + (size_t)node*128 + c;
  float4 A0 = *(const float4*)ps;      // self term
  float4 A1 = *(const float4*)(ps + 4);
  int e = rowptr[node], end = rowptr[node+1];
  for (; e + 4 <= end; e += 4){
    int s0 = csr[e], s1 = csr[e+1], s2 = csr[e+2], s3 = csr[e+3];
    const float* q0 = pc + (size_t)s0*128;
    const float* q1 = pc + (size_t)s1*128;
    const float* q2 = pc + (size_t)s2*128;
    const float* q3 = pc + (size_t)s3*128;
    float4 a0 = *(const float4*)q0, b0 = *(const float4*)(q0+4);
    float4 a1 = *(const float4*)q1, b1 = *(const float4*)(q1+4);
    float4 a2 = *(const float4*)q2, b2 = *(const float4*)(q2+4);
    float4 a3 = *(const float4*)q3, b3 = *(const float4*)(q3+4);
    A0.x += a0.x+a1.x+a2.x+a3.x; A0.y += a0.y+a1.y+a2.y+a3.y;
    A0.z += a0.z+a1.z+a2.z+a3.z; A0.w += a0.w+a1.w+a2.w+a3.w;
    A1.x += b0.x+b1.x+b2.x+b3.x; A1.y += b0.y+b1.y+b2.y+b3.y;
    A1.z += b0.z+b1.z+b2.z+b3.z; A1.w += b0.w+b1.w+b2.w+b3.w;
  }
  for (; e < end; ++e){
    const float* q = pc + (size_t)csr[e]*128;
    float4 a = *(const float4*)q, b = *(const float4*)(q+4);
    A0.x += a.x; A0.y += a.y; A0.z += a.z; A0.w += a.w;
    A1.x += b.x; A1.y += b.y; A1.z += b.z; A1.w += b.w;
  }
  float d = dinv[node];
  float4 o0 = {fmaxf(d*A0.x + bias[c],   0.f), fmaxf(d*A0.y + bias[c+1], 0.f),
               fmaxf(d*A0.z + bias[c+2], 0.f), fmaxf(d*A0.w + bias[c+3], 0.f)};
  float4 o1 = {fmaxf(d*A1.x + bias[c+4], 0.f), fmaxf(d*A1.y + bias[c+5], 0.f),
               fmaxf(d*A1.z + bias[c+6], 0.f), fmaxf(d*A1.w + bias[c+7], 0.f)};
  float* op = out + (size_t)node*128 + c;
  *(float4*)op = o0;
  *(float4*)(op + 4) = o1;
}

// ---------------- last 128-wide agg fused with W3 projection: p5[n] = dinv[n]*dot(relu(...), W3) ----------------
__global__ __launch_bounds__(256) void k_agg_last(const float* __restrict__ p, const int* __restrict__ rowptr,
                                                  const int* __restrict__ csr, const float* __restrict__ dinv,
                                                  const float* __restrict__ bias, const float* __restrict__ W3,
                                                  float* __restrict__ p5, int N){
  const int tid = threadIdx.x;
  const int node = blockIdx.x*16 + (tid >> 4);
  if (node >= N) return;
  const int c = (tid & 15) * 8;
  const float* pc = p + c;
  const float* ps = p + (size_t)node*128 + c;
  float4 A0 = *(const float4*)ps;
  float4 A1 = *(const float4*)(ps + 4);
  int e = rowptr[node], end = rowptr[node+1];
  for (; e + 4 <= end; e += 4){
    int s0 = csr[e], s1 = csr[e+1], s2 = csr[e+2], s3 = csr[e+3];
    const float* q0 = pc + (size_t)s0*128;
    const float* q1 = pc + (size_t)s1*128;
    const float* q2 = pc + (size_t)s2*128;
    const float* q3 = pc + (size_t)s3*128;
    float4 a0 = *(const float4*)q0, b0 = *(const float4*)(q0+4);
    float4 a1 = *(const float4*)q1, b1 = *(const float4*)(q1+4);
    float4 a2 = *(const float4*)q2, b2 = *(const float4*)(q2+4);
    float4 a3 = *(const float4*)q3, b3 = *(const float4*)(q3+4);
    A0.x += a0.x+a1.x+a2.x+a3.x; A0.y += a0.y+a1.y+a2.y+a3.y;
    A0.z += a0.z+a1.z+a2.z+a3.z; A0.w += a0.w+a1.w+a2.w+a3.w;
    A1.x += b0.x+b1.x+b2.x+b3.x; A1.y += b0.y+b1.y+b2.y+b3.y;
    A1.z += b0.z+b1.z+b2.z+b3.z; A1.w += b0.w+b1.w+b2.w+b3.w;
  }
  for (; e < end; ++e){
    const float* q = pc + (size_t)csr[e]*128;
    float4 a = *(const float4*)q, b = *(const float4*)(q+4);
    A0.x += a.x; A0.y += a.y; A0.z += a.z; A0.w += a.w;
    A1.x += b.x; A1.y += b.y; A1.z += b.z; A1.w += b.w;
  }
  float d = dinv[node];
  float o[8];
  o[0] = fmaxf(d*A0.x + bias[c],   0.f); o[1] = fmaxf(d*A0.y + bias[c+1], 0.f);
  o[2] = fmaxf(d*A0.z + bias[c+2], 0.f); o[3] = fmaxf(d*A0.w + bias[c+3], 0.f);
  o[4] = fmaxf(d*A1.x + bias[c+4], 0.f); o[5] = fmaxf(d*A1.y + bias[c+5], 0.f);
  o[6] = fmaxf(d*A1.z + bias[c+6], 0.f); o[7] = fmaxf(d*A1.w + bias[c+7], 0.f);
  float4 w0 = *(const float4*)(W3 + c);
  float4 w1 = *(const float4*)(W3 + c + 4);
  float s = o[0]*w0.x + o[1]*w0.y + o[2]*w0.z + o[3]*w0.w
          + o[4]*w1.x + o[5]*w1.y + o[6]*w1.z + o[7]*w1.w;
  #pragma unroll
  for (int m = 8; m >= 1; m >>= 1) s += __shfl_xor(s, m, 16);
  if ((tid & 15) == 0) p5[node] = d * s;
}

// ---------------- final scalar aggregation ----------------
__global__ __launch_bounds__(256) void k_agg1(const float* __restrict__ p5, const int* __restrict__ rowptr,
                                              const int* __restrict__ csr, const float* __restrict__ dinv,
                                              const float* __restrict__ b3, float* __restrict__ out, int N){
  int n = blockIdx.x*256 + threadIdx.x;
  if (n >= N) return;
  int e = rowptr[n], end = rowptr[n+1];
  float acc = p5[n];
  for (; e + 4 <= end; e += 4)
    acc += p5[csr[e]] + p5[csr[e+1]] + p5[csr[e+2]] + p5[csr[e+3]];
  for (; e < end; ++e) acc += p5[csr[e]];
  out[n] = dinv[n]*acc + b3[0];
}

extern "C" void kernel_launch(void* const* d_in, const int* in_sizes, int n_in,
                              void* d_out, int out_size, void* d_ws, size_t ws_size,
                              hipStream_t stream){
  const float* x  = (const float*)d_in[0];
  const int*   ei = (const int*)  d_in[1];
  const float* W1 = (const float*)d_in[2];
  const float* b1 = (const float*)d_in[3];
  const float* W2 = (const float*)d_in[4];
  const float* b2 = (const float*)d_in[5];
  const float* W3 = (const float*)d_in[6];
  const float* b3 = (const float*)d_in[7];
  float* out = (float*)d_out;

  const int N = in_sizes[0] / 64;
  const int E = in_sizes[1] / 2;
  const int L = in_sizes[4] / (128*128);
  const int* src = ei;
  const int* dst = ei + E;

  char* ws = (char*)d_ws;
  size_t off = 0;
  auto alloc = [&](size_t bytes){ void* p = ws + off; off += (bytes + 255) & ~(size_t)255; return p; };
  int*   counts = (int*)  alloc((size_t)N*4);
  int*   fillc  = (int*)  alloc((size_t)N*4);
  int*   rowptr = (int*)  alloc((size_t)(N+1)*4);
  int*   bsum   = (int*)  alloc(128*4);
  int*   boff   = (int*)  alloc(128*4);
  float* dinv   = (float*)alloc((size_t)N*4);
  float* p5     = (float*)alloc((size_t)N*4);
  int*   csr    = (int*)  alloc((size_t)E*4);
  float* bufA   = (float*)alloc((size_t)N*128*4);
  float* bufB   = (float*)alloc((size_t)N*128*4);
  (void)ws_size; (void)n_in; (void)out_size;

  hipMemsetAsync(counts, 0, (size_t)N*4, stream);
  hipMemsetAsync(fillc,  0, (size_t)N*4, stream);

  k_count<<<DIV_UP(E,256),256,0,stream>>>(dst, counts, E);
  k_dinv <<<DIV_UP(N,256),256,0,stream>>>(counts, dinv, N);
  int nb = DIV_UP(N,1024);
  k_scan1<<<nb,1024,0,stream>>>(counts, rowptr, bsum, N);
  k_scan2<<<1,128,0,stream>>>(bsum, boff, nb, rowptr, N);
  k_scan3<<<nb,1024,0,stream>>>(rowptr, boff, N);
  k_fill <<<DIV_UP(E,256),256,0,stream>>>(src, dst, rowptr, fillc, csr, E);

  // layer 1: aggregate raw x (64-wide, dinv fused), then GEMM 64->128 with bias+relu
  k_agg64x<<<DIV_UP(N,16),256,0,stream>>>(x, rowptr, csr, dinv, bufB, N);
  k_gemm2<64><<<DIV_UP(N,128),256,0,stream>>>(bufB, W1, b1, nullptr, bufA, N, 1);

  // layers 2..4: GEMM (p = dinv*(h@W)), then gather-agg (+bias+relu); last agg fuses W3 projection
  for (int i = 0; i < L; ++i){
    k_gemm2<128><<<DIV_UP(N,128),256,0,stream>>>(bufA, W2 + (size_t)i*128*128, nullptr, dinv, bufB, N, 0);
    if (i < L-1)
      k_agg128<<<DIV_UP(N,16),256,0,stream>>>(bufB, rowptr, csr, dinv, b2 + (size_t)i*128, bufA, N);
    else
      k_agg_last<<<DIV_UP(N,16),256,0,stream>>>(bufB, rowptr, csr, dinv, b2 + (size_t)i*128, W3, p5, N);
  }

  // output layer: scalar gather of p5
  k_agg1<<<DIV_UP(N,256),256,0,stream>>>(p5, rowptr, csr, dinv, b3, out, N);
}

// Round 3
// 862.767 us; speedup vs baseline: 1.1218x; 1.1218x over previous
//
#include <hip/hip_runtime.h>
#include <hip/hip_bf16.h>

#define DIV_UP(a,b) (((a)+(b)-1)/(b))

// ---------------- preprocessing: degree, dinv, CSR-by-dst ----------------

__global__ __launch_bounds__(256) void k_count(const int* __restrict__ dst, int* __restrict__ counts, int E){
  int e = blockIdx.x*256 + threadIdx.x;
  if (e < E) atomicAdd(&counts[dst[e]], 1);
}

__global__ __launch_bounds__(256) void k_dinv(const int* __restrict__ counts, float* __restrict__ dinv, int N){
  int n = blockIdx.x*256 + threadIdx.x;
  if (n < N) dinv[n] = rsqrtf((float)(counts[n] + 1));  // +1 = self-loop
}

__global__ __launch_bounds__(1024) void k_scan1(const int* __restrict__ counts, int* __restrict__ rowptr,
                                                int* __restrict__ bsum, int N){
  __shared__ int s[1024];
  int t = threadIdx.x, g = blockIdx.x*1024 + t;
  int v = (g < N) ? counts[g] : 0;
  s[t] = v; __syncthreads();
  for (int off = 1; off < 1024; off <<= 1){
    int u = (t >= off) ? s[t-off] : 0; __syncthreads();
    s[t] += u; __syncthreads();
  }
  if (g < N) rowptr[g] = s[t] - v;           // block-local exclusive scan
  if (t == 1023) bsum[blockIdx.x] = s[1023];
}

__global__ __launch_bounds__(128) void k_scan2(const int* __restrict__ bsum, int* __restrict__ boff,
                                               int nb, int* __restrict__ rowptr, int N){
  __shared__ int s[128];
  int t = threadIdx.x;
  int v = (t < nb) ? bsum[t] : 0;
  s[t] = v; __syncthreads();
  for (int off = 1; off < 128; off <<= 1){
    int u = (t >= off) ? s[t-off] : 0; __syncthreads();
    s[t] += u; __syncthreads();
  }
  if (t < nb) boff[t] = s[t] - v;            // exclusive over block sums
  if (t == 127) rowptr[N] = s[127];          // total = E
}

__global__ __launch_bounds__(1024) void k_scan3(int* __restrict__ rowptr, const int* __restrict__ boff, int N){
  int g = blockIdx.x*1024 + threadIdx.x;
  if (g < N) rowptr[g] += boff[blockIdx.x];
}

__global__ __launch_bounds__(256) void k_fill(const int* __restrict__ src, const int* __restrict__ dst,
                                              const int* __restrict__ rowptr, int* __restrict__ fill,
                                              int* __restrict__ csr, int E){
  int e = blockIdx.x*256 + threadIdx.x;
  if (e < E){
    int d = dst[e];
    int pos = rowptr[d] + atomicAdd(&fill[d], 1);
    csr[pos] = src[e];
  }
}

// ---------------- fused 64-wide aggregation of raw x: out = dinv[n]*(sum dinv[s]x[s] + dinv[n]x[n]) ----------------
__global__ __launch_bounds__(256) void k_agg64x(const float* __restrict__ x, const int* __restrict__ rowptr,
                                                const int* __restrict__ csr, const float* __restrict__ dinv,
                                                float* __restrict__ out, int N){
  const int tid = threadIdx.x;
  const int node = blockIdx.x*16 + (tid >> 4);
  if (node >= N) return;
  const int c = (tid & 15) * 4;
  const float* xc = x + c;
  const float dn = dinv[node];
  float4 s = *(const float4*)(x + (size_t)node*64 + c);
  float ax = dn*s.x, ay = dn*s.y, az = dn*s.z, aw = dn*s.w;  // self term (dinv[n]*x[n])
  int e = rowptr[node], end = rowptr[node+1];
  for (; e + 4 <= end; e += 4){
    int s0 = csr[e], s1 = csr[e+1], s2 = csr[e+2], s3 = csr[e+3];
    float d0 = dinv[s0], d1 = dinv[s1], d2 = dinv[s2], d3 = dinv[s3];
    float4 v0 = *(const float4*)(xc + (size_t)s0*64);
    float4 v1 = *(const float4*)(xc + (size_t)s1*64);
    float4 v2 = *(const float4*)(xc + (size_t)s2*64);
    float4 v3 = *(const float4*)(xc + (size_t)s3*64);
    ax += d0*v0.x + d1*v1.x + d2*v2.x + d3*v3.x;
    ay += d0*v0.y + d1*v1.y + d2*v2.y + d3*v3.y;
    az += d0*v0.z + d1*v1.z + d2*v2.z + d3*v3.z;
    aw += d0*v0.w + d1*v1.w + d2*v2.w + d3*v3.w;
  }
  for (; e < end; ++e){
    int s0 = csr[e];
    float d0 = dinv[s0];
    float4 v = *(const float4*)(xc + (size_t)s0*64);
    ax += d0*v.x; ay += d0*v.y; az += d0*v.z; aw += d0*v.w;
  }
  float4 o = {dn*ax, dn*ay, dn*az, dn*aw};
  *(float4*)(out + (size_t)node*64 + c) = o;
}

// ---------------- GEMM: out[N,128] = H[N,FIN] @ W[FIN,128]; 64x128 tile, 128 thr, 8x8 micro ----------------
template<int FIN>
__global__ __launch_bounds__(128) void k_gemm3(const float* __restrict__ H, const float* __restrict__ W,
                                               const float* __restrict__ bias, const float* __restrict__ dinv,
                                               float* __restrict__ out, int N, int relu){
  constexpr int KC = 32;
  __shared__ float At[KC][65];    // transposed A chunk: At[k][row], +1 pad
  __shared__ float Bs[KC][128];   // W chunk
  const int tid = threadIdx.x;
  const int tr = tid >> 4, tc = tid & 15;   // rows 8tr..8tr+7; cols {4tc..4tc+3, 64+4tc..64+4tc+3}
  const int row0 = blockIdx.x * 64;

  float acc[8][8];
  #pragma unroll
  for (int i = 0; i < 8; ++i)
    #pragma unroll
    for (int j = 0; j < 8; ++j) acc[i][j] = 0.f;

  for (int k0 = 0; k0 < FIN; k0 += KC){
    // stage A: coalesced read, transposed write (banks (c4+j+rr)%32 -> 2-way, free)
    #pragma unroll
    for (int it = 0; it < 4; ++it){
      int idx = it*128 + tid;      // 0..511
      int rr = idx >> 3;           // 0..63
      int c4 = (idx & 7) * 4;      // 0..28
      int grow = row0 + rr; if (grow >= N) grow = N - 1;
      float4 v = *(const float4*)(H + (size_t)grow*FIN + k0 + c4);
      At[c4+0][rr] = v.x; At[c4+1][rr] = v.y; At[c4+2][rr] = v.z; At[c4+3][rr] = v.w;
    }
    // stage B
    #pragma unroll
    for (int it = 0; it < 8; ++it){
      int idx = it*512 + tid*4;
      int kk = idx >> 7, cc = idx & 127;
      *(float4*)&Bs[kk][cc] = *(const float4*)(W + (size_t)(k0+kk)*128 + cc);
    }
    __syncthreads();
    #pragma unroll 8
    for (int kk = 0; kk < KC; ++kk){
      float4 a0 = *(const float4*)&At[kk][8*tr];
      float4 a1 = *(const float4*)&At[kk][8*tr + 4];
      float4 b0 = *(const float4*)&Bs[kk][4*tc];
      float4 b1 = *(const float4*)&Bs[kk][64 + 4*tc];
      float a[8] = {a0.x,a0.y,a0.z,a0.w,a1.x,a1.y,a1.z,a1.w};
      float b[8] = {b0.x,b0.y,b0.z,b0.w,b1.x,b1.y,b1.z,b1.w};
      #pragma unroll
      for (int i = 0; i < 8; ++i)
        #pragma unroll
        for (int j = 0; j < 8; ++j)
          acc[i][j] += a[i]*b[j];
    }
    __syncthreads();
  }

  float bl[8] = {0,0,0,0,0,0,0,0};
  if (bias){
    #pragma unroll
    for (int j = 0; j < 4; ++j){ bl[j] = bias[4*tc + j]; bl[4+j] = bias[64 + 4*tc + j]; }
  }
  #pragma unroll
  for (int i = 0; i < 8; ++i){
    int r = row0 + 8*tr + i;
    if (r < N){
      float sc = dinv ? dinv[r] : 1.f;
      float o[8];
      #pragma unroll
      for (int j = 0; j < 8; ++j){
        o[j] = acc[i][j]*sc + bl[j];
        if (relu) o[j] = fmaxf(o[j], 0.f);
      }
      float4 u0 = {o[0],o[1],o[2],o[3]}, u1 = {o[4],o[5],o[6],o[7]};
      *(float4*)(out + (size_t)r*128 + 4*tc)      = u0;
      *(float4*)(out + (size_t)r*128 + 64 + 4*tc) = u1;
    }
  }
}

// ---------------- 128-wide CSR aggregation (R1 shape: 32 lanes/node): out[n]=relu(dinv*(sum+self)+b) ----------------
__global__ __launch_bounds__(256) void k_agg128(const float* __restrict__ p, const int* __restrict__ rowptr,
                                                const int* __restrict__ csr, const float* __restrict__ dinv,
                                                const float* __restrict__ bias, float* __restrict__ out, int N){
  const int tid = threadIdx.x;
  const int node = blockIdx.x*8 + (tid >> 5);
  if (node >= N) return;
  const int c = (tid & 31) * 4;
  const float* pc = p + c;
  int e = rowptr[node], end = rowptr[node+1];
  float4 s = *(const float4*)(p + (size_t)node*128 + c);   // self term
  float ax = s.x, ay = s.y, az = s.z, aw = s.w;
  for (; e + 4 <= end; e += 4){
    int s0 = csr[e], s1 = csr[e+1], s2 = csr[e+2], s3 = csr[e+3];
    float4 v0 = *(const float4*)(pc + (size_t)s0*128);
    float4 v1 = *(const float4*)(pc + (size_t)s1*128);
    float4 v2 = *(const float4*)(pc + (size_t)s2*128);
    float4 v3 = *(const float4*)(pc + (size_t)s3*128);
    ax += v0.x+v1.x+v2.x+v3.x; ay += v0.y+v1.y+v2.y+v3.y;
    az += v0.z+v1.z+v2.z+v3.z; aw += v0.w+v1.w+v2.w+v3.w;
  }
  for (; e < end; ++e){
    float4 v = *(const float4*)(pc + (size_t)csr[e]*128);
    ax += v.x; ay += v.y; az += v.z; aw += v.w;
  }
  float d = dinv[node];
  float4 o = {fmaxf(d*ax + bias[c],   0.f), fmaxf(d*ay + bias[c+1], 0.f),
              fmaxf(d*az + bias[c+2], 0.f), fmaxf(d*aw + bias[c+3], 0.f)};
  *(float4*)(out + (size_t)node*128 + c) = o;
}

// ---------------- last 128-wide agg fused with W3 projection (32 lanes/node) ----------------
__global__ __launch_bounds__(256) void k_agg_last(const float* __restrict__ p, const int* __restrict__ rowptr,
                                                  const int* __restrict__ csr, const float* __restrict__ dinv,
                                                  const float* __restrict__ bias, const float* __restrict__ W3,
                                                  float* __restrict__ p5, int N){
  const int tid = threadIdx.x;
  const int node = blockIdx.x*8 + (tid >> 5);
  if (node >= N) return;
  const int c = (tid & 31) * 4;
  const float* pc = p + c;
  int e = rowptr[node], end = rowptr[node+1];
  float4 s = *(const float4*)(p + (size_t)node*128 + c);
  float ax = s.x, ay = s.y, az = s.z, aw = s.w;
  for (; e + 4 <= end; e += 4){
    int s0 = csr[e], s1 = csr[e+1], s2 = csr[e+2], s3 = csr[e+3];
    float4 v0 = *(const float4*)(pc + (size_t)s0*128);
    float4 v1 = *(const float4*)(pc + (size_t)s1*128);
    float4 v2 = *(const float4*)(pc + (size_t)s2*128);
    float4 v3 = *(const float4*)(pc + (size_t)s3*128);
    ax += v0.x+v1.x+v2.x+v3.x; ay += v0.y+v1.y+v2.y+v3.y;
    az += v0.z+v1.z+v2.z+v3.z; aw += v0.w+v1.w+v2.w+v3.w;
  }
  for (; e < end; ++e){
    float4 v = *(const float4*)(pc + (size_t)csr[e]*128);
    ax += v.x; ay += v.y; az += v.z; aw += v.w;
  }
  float d = dinv[node];
  float o0 = fmaxf(d*ax + bias[c],   0.f);
  float o1 = fmaxf(d*ay + bias[c+1], 0.f);
  float o2 = fmaxf(d*az + bias[c+2], 0.f);
  float o3 = fmaxf(d*aw + bias[c+3], 0.f);
  float4 w = *(const float4*)(W3 + c);
  float sdot = o0*w.x + o1*w.y + o2*w.z + o3*w.w;
  #pragma unroll
  for (int m = 16; m >= 1; m >>= 1) sdot += __shfl_xor(sdot, m, 32);
  if ((tid & 31) == 0) p5[node] = d * sdot;
}

// ---------------- final scalar aggregation ----------------
__global__ __launch_bounds__(256) void k_agg1(const float* __restrict__ p5, const int* __restrict__ rowptr,
                                              const int* __restrict__ csr, const float* __restrict__ dinv,
                                              const float* __restrict__ b3, float* __restrict__ out, int N){
  int n = blockIdx.x*256 + threadIdx.x;
  if (n >= N) return;
  int e = rowptr[n], end = rowptr[n+1];
  float acc = p5[n];
  for (; e + 4 <= end; e += 4)
    acc += p5[csr[e]] + p5[csr[e+1]] + p5[csr[e+2]] + p5[csr[e+3]];
  for (; e < end; ++e) acc += p5[csr[e]];
  out[n] = dinv[n]*acc + b3[0];
}

extern "C" void kernel_launch(void* const* d_in, const int* in_sizes, int n_in,
                              void* d_out, int out_size, void* d_ws, size_t ws_size,
                              hipStream_t stream){
  const float* x  = (const float*)d_in[0];
  const int*   ei = (const int*)  d_in[1];
  const float* W1 = (const float*)d_in[2];
  const float* b1 = (const float*)d_in[3];
  const float* W2 = (const float*)d_in[4];
  const float* b2 = (const float*)d_in[5];
  const float* W3 = (const float*)d_in[6];
  const float* b3 = (const float*)d_in[7];
  float* out = (float*)d_out;

  const int N = in_sizes[0] / 64;
  const int E = in_sizes[1] / 2;
  const int L = in_sizes[4] / (128*128);
  const int* src = ei;
  const int* dst = ei + E;

  char* ws = (char*)d_ws;
  size_t off = 0;
  auto alloc = [&](size_t bytes){ void* p = ws + off; off += (bytes + 255) & ~(size_t)255; return p; };
  int*   counts = (int*)  alloc((size_t)N*4);
  int*   fillc  = (int*)  alloc((size_t)N*4);
  int*   rowptr = (int*)  alloc((size_t)(N+1)*4);
  int*   bsum   = (int*)  alloc(128*4);
  int*   boff   = (int*)  alloc(128*4);
  float* dinv   = (float*)alloc((size_t)N*4);
  float* p5     = (float*)alloc((size_t)N*4);
  int*   csr    = (int*)  alloc((size_t)E*4);
  float* bufA   = (float*)alloc((size_t)N*128*4);
  float* bufB   = (float*)alloc((size_t)N*128*4);
  (void)ws_size; (void)n_in; (void)out_size;

  hipMemsetAsync(counts, 0, (size_t)N*4, stream);
  hipMemsetAsync(fillc,  0, (size_t)N*4, stream);

  k_count<<<DIV_UP(E,256),256,0,stream>>>(dst, counts, E);
  k_dinv <<<DIV_UP(N,256),256,0,stream>>>(counts, dinv, N);
  int nb = DIV_UP(N,1024);
  k_scan1<<<nb,1024,0,stream>>>(counts, rowptr, bsum, N);
  k_scan2<<<1,128,0,stream>>>(bsum, boff, nb, rowptr, N);
  k_scan3<<<nb,1024,0,stream>>>(rowptr, boff, N);
  k_fill <<<DIV_UP(E,256),256,0,stream>>>(src, dst, rowptr, fillc, csr, E);

  // layer 1: aggregate raw x (64-wide, dinv fused), then GEMM 64->128 with bias+relu
  k_agg64x<<<DIV_UP(N,16),256,0,stream>>>(x, rowptr, csr, dinv, bufB, N);
  k_gemm3<64><<<DIV_UP(N,64),128,0,stream>>>(bufB, W1, b1, nullptr, bufA, N, 1);

  // layers 2..4: GEMM (p = dinv*(h@W)), then gather-agg (+bias+relu); last agg fuses W3 projection
  for (int i = 0; i < L; ++i){
    k_gemm3<128><<<DIV_UP(N,64),128,0,stream>>>(bufA, W2 + (size_t)i*128*128, nullptr, dinv, bufB, N, 0);
    if (i < L-1)
      k_agg128<<<DIV_UP(N,8),256,0,stream>>>(bufB, rowptr, csr, dinv, b2 + (size_t)i*128, bufA, N);
    else
      k_agg_last<<<DIV_UP(N,8),256,0,stream>>>(bufB, rowptr, csr, dinv, b2 + (size_t)i*128, W3, p5, N);
  }

  // output layer: scalar gather of p5
  k_agg1<<<DIV_UP(N,256),256,0,stream>>>(p5, rowptr, csr, dinv, b3, out, N);
}